// Round 13
// baseline (239.650 us; speedup 1.0000x reference)
//
#include <hip/hip_runtime.h>
#include <stdint.h>

#define NB   8192
#define DIN  512
#define NH1  4096
#define NH2  4096
#define NA   64

typedef int v4i __attribute__((ext_vector_type(4)));

__device__ __forceinline__ v4i mfma_i8(v4i a, v4i b, v4i c) {
    return __builtin_amdgcn_mfma_i32_16x16x64_i8(a, b, c, 0, 0, 0);
}

// ---- async global->LDS, 16B per lane (dest = wave-uniform base + lane*16) ----
__device__ __forceinline__ void gload16(const void* g, const void* l) {
    __builtin_amdgcn_global_load_lds(
        (const __attribute__((address_space(1))) void*)(uintptr_t)g,
        (__attribute__((address_space(3))) void*)(uint32_t)(uintptr_t)l,
        16, 0, 0);
}

// fragment-layout convert: unit u=(g,kt,l): out[u*16+b] = round(in[16g+(l&15)][64kt+(l>>4)*16+b])
__device__ __forceinline__ void frag_unit(const float* __restrict__ in, signed char* __restrict__ out,
                                          int u, int K, int ktmask, int gshift) {
    const int g   = u >> gshift;
    const int kt  = (u >> 6) & ktmask;
    const int l   = u & 63;
    const int row = g * 16 + (l & 15);
    const int k0  = kt * 64 + (l >> 4) * 16;
    const float4* src = (const float4*)(in + (size_t)row * K + k0);
    signed char v[16];
    #pragma unroll
    for (int q = 0; q < 4; ++q) {
        const float4 f = src[q];
        v[q*4+0] = (signed char)__float2int_rn(f.x);
        v[q*4+1] = (signed char)__float2int_rn(f.y);
        v[q*4+2] = (signed char)__float2int_rn(f.z);
        v[q*4+3] = (signed char)__float2int_rn(f.w);
    }
    *(int4*)(out + (size_t)u * 16) = *(const int4*)v;
}

// ---------------- merged prep: all fragment converts + wp + sum_wp in ONE launch ----------------
// [0,4096): w2->frag | [4096,4608): w1->frag | [4608,5632): x->frag
// [5632,5888): wp row-major i8 | [5888,5952): sum_wp
__global__ __launch_bounds__(256)
void prep(const float* __restrict__ x,  const float* __restrict__ w1,
          const float* __restrict__ w2, const float* __restrict__ wp,
          signed char* __restrict__ xf, signed char* __restrict__ w1f,
          signed char* __restrict__ w2f, signed char* __restrict__ wp_i8,
          int* __restrict__ S)
{
    __shared__ int red[256];
    const int b   = blockIdx.x;
    const int tid = threadIdx.x;

    if (b < 4096) {                 // w2 (4096x4096): KT=64 -> ktmask 63, gshift 12
        frag_unit(w2, w2f, b * 256 + tid, NH1, 63, 12);
    } else if (b < 4608) {          // w1 (4096x512): KT=8 -> ktmask 7, gshift 9
        frag_unit(w1, w1f, (b - 4096) * 256 + tid, DIN, 7, 9);
    } else if (b < 5632) {          // x (8192x512): KT=8
        frag_unit(x, xf, (b - 4608) * 256 + tid, DIN, 7, 9);
    } else if (b < 5888) {          // wp row-major i8 (64 x 4096)
        const int i = (b - 5632) * 256 + tid;          // 65536 char4 units
        const float4 v = ((const float4*)wp)[i];
        char4 c;
        c.x = (signed char)__float2int_rn(v.x);
        c.y = (signed char)__float2int_rn(v.y);
        c.z = (signed char)__float2int_rn(v.z);
        c.w = (signed char)__float2int_rn(v.w);
        ((char4*)wp_i8)[i] = c;
    } else {                        // sum_wp: S[a] = sum_k round(wp[a][k])
        const int a = b - 5888;
        int p = 0;
        for (int k = tid; k < NH2; k += 256) p += __float2int_rn(wp[(size_t)a * NH2 + k]);
        red[tid] = p; __syncthreads();
        for (int s = 128; s > 0; s >>= 1) { if (tid < s) red[tid] += red[tid + s]; __syncthreads(); }
        if (tid == 0) S[a] = red[0];
    }
}

// ---------------- i8 GEMM, BOTH operands in FRAGMENT layout, barrier-free K-loop ----------------
// 256x128 tile, BK=64, 8 waves (4Mx2N, wave 64x64), 2 blocks/CU.
// K-loop has NO LDS, NO barriers, NO inline asm: 8 coalesced global_load_dwordx4 (L2-hit)
// + 16 MFMA per wave per tile. Waves drift freely; compiler pipelines loads itself.
// LDS used only by the (proven) epilogue.
// EPI=1: h1q -> out0 in FRAGMENT layout
// EPI=2: rr = relu(round(M*(acc+b))); out0=(rr&255)-128, out1=(rr>>8)-128 row-major planes
template <int EPI>
__global__ __launch_bounds__(512, 4)
void gemm_ff(const signed char* __restrict__ Af,
             const signed char* __restrict__ Bf,
             int M, int N, int K,
             const float* __restrict__ bias,
             const float* __restrict__ Mscale,
             const float* __restrict__ qscale,
             signed char* __restrict__ out0,
             signed char* __restrict__ out1)
{
    __shared__ __align__(16) signed char lds[69632];   // epilogue img planes only

    const int tid  = threadIdx.x;
    const int lane = tid & 63;
    const int wid  = tid >> 6;
    const int wm   = wid >> 1, wn = wid & 1;   // 4M x 2N waves, 64x64 each

    // XCD-aware bijective swizzle (grid divisible by 8), N-fastest:
    // co-resident blocks share the A row-panel (L1/L2-served af)
    const int nwg  = gridDim.x;
    const int bid  = blockIdx.x;
    const int swzb = (bid & 7) * (nwg >> 3) + (bid >> 3);
    const int nbx  = N >> 7;
    const int bx   = swzb % nbx;
    const int by   = swzb / nbx;
    const int bm0  = by << 8, bn0 = bx << 7;

    const int NKT = K >> 6;
    const signed char* afBase = Af + (((size_t)((bm0 >> 4) + wm * 4) * NKT) << 10) + lane * 16;
    const signed char* bfBase = Bf + (((size_t)((bn0 >> 4) + wn * 4) * NKT) << 10) + lane * 16;

    v4i acc[4][4] = {};

    #pragma unroll 2
    for (int t = 0; t < NKT; ++t) {
        v4i af[4], bf[4];
        #pragma unroll
        for (int m = 0; m < 4; ++m)
            af[m] = *(const v4i*)(afBase + ((size_t)(m * NKT + t) << 10));
        #pragma unroll
        for (int n = 0; n < 4; ++n)
            bf[n] = *(const v4i*)(bfBase + ((size_t)(n * NKT + t) << 10));

        __builtin_amdgcn_s_setprio(1);
        #pragma unroll
        for (int m = 0; m < 4; ++m)
            #pragma unroll
            for (int n = 0; n < 4; ++n)
                acc[m][n] = mfma_i8(af[m], bf[n], acc[m][n]);
        __builtin_amdgcn_s_setprio(0);
    }

    // ---- epilogue: LDS img [256][136] per plane (proven, 0 conflicts) ----
    signed char* img0 = lds;
    signed char* img1 = lds + 34816;
    const int rowb = wm * 64 + ((lane >> 4) << 2);
    const int colb = wn * 64 + (lane & 15);

    if constexpr (EPI == 1) {
        const float Mv = Mscale[0];
        const float sv = qscale[0];
        #pragma unroll
        for (int n = 0; n < 4; ++n) {
            const int col  = colb + n * 16;
            const int bint = __float2int_rn(bias[bn0 + col]);
            #pragma unroll
            for (int m = 0; m < 4; ++m) {
                #pragma unroll
                for (int j = 0; j < 4; ++j) {
                    const int row  = rowb + m * 16 + j;
                    const int accv = acc[m][n][j] + bint;      // |acc1| <= 8.4M: f32-exact
                    float h = rintf(Mv * (float)accv);
                    h = fmaxf(h, 0.0f);
                    float q = rintf(h / sv);
                    q = fminf(fmaxf(q, -128.0f), 127.0f);
                    img0[row * 136 + col] = (signed char)(int)q;
                }
            }
        }
        __syncthreads();
        // flush to FRAGMENT layout for GEMM2's A-side
        const int oNKT = N >> 6;
        #pragma unroll
        for (int i = 0; i < 4; ++i) {
            const int u    = i * 512 + tid;        // 2048 units x 16B
            const int g_l  = u >> 7;
            const int kt_l = (u >> 6) & 1;
            const int l    = u & 63;
            const int lrow = g_l * 16 + (l & 15);
            const int lcol = kt_l * 64 + (l >> 4) * 16;
            const size_t g  = (size_t)((bm0 >> 4) + g_l);
            const size_t kt = (size_t)((bn0 >> 6) + kt_l);
            *(int4*)(out0 + ((g * oNKT + kt) << 10) + l * 16) =
                *(const int4*)(img0 + lrow * 136 + lcol);
        }
    } else {
        const float Mv = Mscale[0];
        #pragma unroll
        for (int n = 0; n < 4; ++n) {
            const int col  = colb + n * 16;
            const int bint = __float2int_rn(bias[bn0 + col]);
            #pragma unroll
            for (int m = 0; m < 4; ++m) {
                #pragma unroll
                for (int j = 0; j < 4; ++j) {
                    const int row  = rowb + m * 16 + j;
                    const int accv = acc[m][n][j] + bint;      // |acc2| <= 66.6M: f64 exact
                    double rr = rint((double)Mv * (double)accv);
                    rr = rr > 0.0 ? rr : 0.0;                  // relu; <= 65024
                    const int v = (int)rr;
                    img0[row * 136 + col] = (signed char)((v & 255) - 128);
                    img1[row * 136 + col] = (signed char)((v >> 8) - 128);
                }
            }
        }
        __syncthreads();
        #pragma unroll
        for (int p = 0; p < 8; ++p) {
            const int idx = p * 512 + tid;
            const int row = idx >> 4;
            const int cb  = (idx & 15) * 8;
            const size_t gaddr = (size_t)(bm0 + row) * N + bn0 + cb;
            *(int2*)(out0 + gaddr) = *(const int2*)(img0 + row * 136 + cb);
            *(int2*)(out1 + gaddr) = *(const int2*)(img1 + row * 136 + cb);
        }
    }
}

// ---------------- head MFMA: partial[kblk][r][a] = 256*Phi + Plo over K-chunk 512 ----------------
__global__ __launch_bounds__(512, 1)
void head_mfma(const signed char* __restrict__ lo,
               const signed char* __restrict__ hi,
               const signed char* __restrict__ wpq,
               int* __restrict__ part)
{
    __shared__ __align__(16) signed char Bl[32768];       // 64 x 512 i8 (swizzled)
    __shared__ __align__(16) signed char Al[3][32768];    // [lo 256x64 | hi 256x64]

    const int tid  = threadIdx.x;
    const int lane = tid & 63;
    const int wid  = tid >> 6;
    const int rblk = blockIdx.x >> 3;
    const int kblk = blockIdx.x & 7;
    const int bm0  = rblk << 8;
    const int kb   = kblk << 9;

    #pragma unroll
    for (int s = 0; s < 4; ++s) {
        const int brow = s * 16 + (tid >> 5);
        const int pch  = tid & 31;
        const int lc   = pch ^ (brow & 7);
        gload16(wpq + (size_t)brow * NH2 + kb + lc * 16, Bl + brow * 512 + pch * 16);
    }

    const int srow  = tid >> 2;
    const int sclog = (tid & 3) ^ ((tid >> 3) & 3);
    const size_t ab = (size_t)(bm0 + srow) * NH2 + kb + sclog * 16;
    const size_t rK = (size_t)128 * NH2;

    #define HSTAGE(bp, ko) do { \
        gload16(lo + ab + (ko),      &Al[bp][0]     + tid * 16); \
        gload16(lo + ab + rK + (ko), &Al[bp][8192]  + tid * 16); \
        gload16(hi + ab + (ko),      &Al[bp][16384] + tid * 16); \
        gload16(hi + ab + rK + (ko), &Al[bp][24576] + tid * 16); } while (0)

    HSTAGE(0, 0);
    HSTAGE(1, 64);

    const int r    = lane & 15;
    const int cg   = lane >> 4;
    const int pcA  = (cg ^ ((r >> 1) & 3)) * 16;
    const int aoff = wid * 2048 + r * 64 + pcA;

    v4i accL[2][4] = {}, accH[2][4] = {};
    int cur = 0, nxt = 2;

    for (int t = 0; t < 8; ++t) {
        if (t < 7) asm volatile("s_waitcnt vmcnt(4)" ::: "memory");
        else       asm volatile("s_waitcnt vmcnt(0)" ::: "memory");
        __builtin_amdgcn_s_barrier();

        const signed char* A = &Al[cur][0];
        v4i bf[4], al[2], ah[2];
        #pragma unroll
        for (int n = 0; n < 4; ++n)
            bf[n] = *(const v4i*)(Bl + (n * 16 + r) * 512 + (((t * 4 + cg) ^ (r & 7)) * 16));
        #pragma unroll
        for (int m = 0; m < 2; ++m) al[m] = *(const v4i*)(A + aoff + m * 1024);
        #pragma unroll
        for (int m = 0; m < 2; ++m) ah[m] = *(const v4i*)(A + 16384 + aoff + m * 1024);

        if (t + 2 < 8) HSTAGE(nxt, (t + 2) << 6);

        __builtin_amdgcn_s_setprio(1);
        #pragma unroll
        for (int m = 0; m < 2; ++m)
            #pragma unroll
            for (int n = 0; n < 4; ++n) {
                accL[m][n] = mfma_i8(al[m], bf[n], accL[m][n]);
                accH[m][n] = mfma_i8(ah[m], bf[n], accH[m][n]);
            }
        __builtin_amdgcn_s_setprio(0);
        __builtin_amdgcn_s_barrier();

        cur = (cur == 2) ? 0 : cur + 1;
        nxt = (nxt == 2) ? 0 : nxt + 1;
    }
    #undef HSTAGE

    int* pb = part + (size_t)kblk * (NB * NA);
    const int rowb = bm0 + wid * 32 + ((lane >> 4) << 2);
    #pragma unroll
    for (int m = 0; m < 2; ++m)
        #pragma unroll
        for (int n = 0; n < 4; ++n) {
            const int a = n * 16 + (lane & 15);
            #pragma unroll
            for (int j = 0; j < 4; ++j) {
                const int row = rowb + m * 16 + j;
                pb[(size_t)row * NA + a] = accL[m][n][j] + (accH[m][n][j] << 8);
            }
        }
}

// ---------------- combine: out = round(Mp*(sum parts + 32896*S[a] + b[a])) ----------------
__global__ __launch_bounds__(256)
void comb_head(const int* __restrict__ part, const int* __restrict__ S,
               const float* __restrict__ bp, const float* __restrict__ Mp,
               float* __restrict__ out)
{
    const int t = blockIdx.x * 256 + threadIdx.x;   // 524288
    const int a = t & 63;
    long long sum = 0;
    #pragma unroll
    for (int c = 0; c < 8; ++c) sum += part[(size_t)c * (NB * NA) + t];
    sum += 32896LL * (long long)S[a] + (long long)__float2int_rn(bp[a]);
    out[t] = (float)rint((double)Mp[0] * (double)sum);
}

// ---------------- launcher ----------------
extern "C" void kernel_launch(void* const* d_in, const int* in_sizes, int n_in,
                              void* d_out, int out_size, void* d_ws, size_t ws_size,
                              hipStream_t stream) {
    const float* x  = (const float*)d_in[0];
    const float* w1 = (const float*)d_in[1];
    const float* b1 = (const float*)d_in[2];
    const float* w2 = (const float*)d_in[3];
    const float* b2 = (const float*)d_in[4];
    const float* wp = (const float*)d_in[7];
    const float* bp = (const float*)d_in[8];
    const float* M1 = (const float*)d_in[9];
    const float* M2 = (const float*)d_in[10];
    const float* Mp = (const float*)d_in[12];
    const float* s2 = (const float*)d_in[13];

    const size_t MB = (size_t)1 << 20;
    char* ws = (char*)d_ws;
    signed char* xf    = (signed char*)(ws);              // 4 MiB   x fragments
    signed char* w1f   = (signed char*)(ws + 4  * MB);    // 2 MiB   w1 fragments
    signed char* w2f   = (signed char*)(ws + 6  * MB);    // 16 MiB  w2 fragments
    signed char* wp_i8 = (signed char*)(ws + 22 * MB);    // 256 KiB row-major
    int*         Ssum  = (int*)        (ws + 22 * MB + 512 * 1024); // 256 B
    signed char* h1f   = (signed char*)(ws + 23 * MB);    // 32 MiB  h1q fragments
    signed char* h2lo  = (signed char*)(ws + 55 * MB);    // 32 MiB
    signed char* h2hi  = (signed char*)(ws + 87 * MB);    // 32 MiB
    int*         part  = (int*)        (ws);              // 16 MiB, overlays xf/w1f/w2f (post-GEMM2)

    // all fragment converts + wp + sum_wp in one launch
    prep<<<dim3(5952), dim3(256), 0, stream>>>(x, w1, w2, wp, xf, w1f, w2f, wp_i8, Ssum);

    // GEMM1: (8192x512 frag) x (4096x512 frag)^T -> h1f (fragment layout)
    gemm_ff<1><<<dim3((NB / 256) * (NH1 / 128)), dim3(512), 0, stream>>>(
        xf, w1f, NB, NH1, DIN, b1, M1, s2, h1f, nullptr);
    // GEMM2: (8192x4096 frag) x (4096x4096 frag)^T -> h2lo/h2hi i8 planes (row-major)
    gemm_ff<2><<<dim3((NB / 256) * (NH2 / 128)), dim3(512), 0, stream>>>(
        h1f, w2f, NB, NH2, NH1, b2, M2, nullptr, h2lo, h2hi);
    // head: 256 blocks (32 row-tiles x 8 K-chunks) -> part, then combine
    head_mfma<<<dim3(256), dim3(512), 0, stream>>>(h2lo, h2hi, wp_i8, part);
    comb_head<<<dim3(NB * NA / 256), dim3(256), 0, stream>>>(part, Ssum, bp, Mp, (float*)d_out);
}